// Round 7
// baseline (43.316 us; speedup 1.0000x reference)
//
#include <hip/hip_runtime.h>
#include <hip/hip_bf16.h>

#define B_TOTAL 2048
#define IN_SZ   288
#define GH      64
#define E_NUM   8
#define OUT_N   256
#define K_TOT   (E_NUM * IN_SZ)   // 2304
#define NKT     9                 // k-tiles of 32 per expert

#define GATE_BLKS 32              // 64 rows each
#define TR_BLKS   72              // one (e, kt) slab each

typedef __attribute__((ext_vector_type(8))) short bf16x8;
typedef __attribute__((ext_vector_type(4))) float f32x4;

__device__ __forceinline__ float elu_f(float x) {
    return x > 0.0f ? x : (expf(x) - 1.0f);
}
__device__ __forceinline__ ushort f2bf(float f) {
    __hip_bfloat16 h = __float2bfloat16(f);
    return *reinterpret_cast<ushort*>(&h);
}

// ================= k1: prep =================
// blocks [0,32): gate MLP for 64 rows each -> coefT[e][b] (r6-validated gate code)
// blocks [32,104): w2 -> fragment-major w2tf. Fragment (e, nt, kt) is 1024 B:
//   lane l's 16 B at offset l*16 holds cols nt*16+(l&15), k = kt*32+(l>>4)*8 .. +7
__global__ __launch_bounds__(256) void prep_kernel(
    const float* __restrict__ z,
    const float* __restrict__ g0_w, const float* __restrict__ g0_b,
    const float* __restrict__ g1_w, const float* __restrict__ g1_b,
    const float* __restrict__ g2_w, const float* __restrict__ g2_b,
    const float* __restrict__ w2,
    float* __restrict__ coefT, ushort* __restrict__ w2tf)
{
    __shared__ char smem[62720];
    const int t = threadIdx.x;

    if (blockIdx.x >= GATE_BLKS) {
        // ---- fragment transpose: one 32-k x 256-col slab of one expert ----
        float (*ts)[260] = (float(*)[260])smem;          // 33280 B
        const int bid = blockIdx.x - GATE_BLKS;          // 0..71
        const int e  = bid / NKT;
        const int kt = bid - e * NKT;
        const float* src = w2 + ((size_t)e * IN_SZ + kt * 32) * OUT_N;
        #pragma unroll
        for (int q = t; q < 2048; q += 256) {            // 32 rows x 64 float4
            int r = q >> 6, c4 = q & 63;
            *(float4*)&ts[r][c4 * 4] = *(const float4*)(src + (size_t)r * OUT_N + c4 * 4);
        }
        __syncthreads();
        #pragma unroll
        for (int it = 0; it < 4; ++it) {
            int q = t + it * 256;                        // 0..1023
            int nt = q >> 6, l = q & 63;
            int fr = l & 15, fg = l >> 4;
            ushort4 u0, u1;
            u0.x = f2bf(ts[fg * 8 + 0][nt * 16 + fr]);
            u0.y = f2bf(ts[fg * 8 + 1][nt * 16 + fr]);
            u0.z = f2bf(ts[fg * 8 + 2][nt * 16 + fr]);
            u0.w = f2bf(ts[fg * 8 + 3][nt * 16 + fr]);
            u1.x = f2bf(ts[fg * 8 + 4][nt * 16 + fr]);
            u1.y = f2bf(ts[fg * 8 + 5][nt * 16 + fr]);
            u1.z = f2bf(ts[fg * 8 + 6][nt * 16 + fr]);
            u1.w = f2bf(ts[fg * 8 + 7][nt * 16 + fr]);
            size_t off = ((size_t)((e * 16 + nt) * NKT + kt)) * 512 + l * 8;
            *(ushort4*)&w2tf[off]     = u0;
            *(ushort4*)&w2tf[off + 4] = u1;
        }
        return;
    }

    // ---- gate branch (r6-validated structure), 64 rows ----
    ushort* zbs  = (ushort*)smem;                   // [64][296] bf16, reused as g0t
    ushort* g0t  = (ushort*)smem;
    ushort* g1t  = (ushort*)(smem + 37888);         // [64][72]
    ushort* g2t  = (ushort*)(smem + 47104);         // [16][72] (rows 8-15 zero)
    float*  lgs  = (float*)(smem + 58624);          // [64][8]

    const int wid = t >> 6, l = t & 63;
    const int r0  = blockIdx.x * 64;
    ushort* hscr = (ushort*)(smem + 49408) + wid * 1152;   // per-wave [16][72]

    const int frow = l & 15;
    const int fk   = (l >> 4) * 8;

    // phase 1: stage zbs (bf16) + g1t + g2t
    for (int q = t; q < 4608; q += 256) {           // 64 rows x 72 float4
        int row = q / 72, c4 = q - row * 72;
        float4 v = *(const float4*)(z + (size_t)(r0 + row) * IN_SZ + c4 * 4);
        ushort4 o4;
        o4.x = f2bf(v.x); o4.y = f2bf(v.y); o4.z = f2bf(v.z); o4.w = f2bf(v.w);
        *(ushort4*)&zbs[row * 296 + c4 * 4] = o4;
    }
    for (int q = t; q < 4096; q += 256) {           // g1_w[i][o] -> g1t[o][i]
        int i = q >> 6, o = q & 63;
        g1t[o * 72 + i] = f2bf(g1_w[q]);
    }
    for (int q = t; q < 512; q += 256) {            // g2_w[i][o] -> g2t[o][i]
        int i = q >> 3, o = q & 7;
        g2t[o * 72 + i] = f2bf(g2_w[q]);
    }
    for (int q = t; q < 576; q += 256) g2t[576 + q] = 0;
    __syncthreads();

    // phase 2: this wave's z fragments (16 rows)
    bf16x8 A[9];
    #pragma unroll
    for (int kk = 0; kk < 9; ++kk)
        A[kk] = *(const bf16x8*)&zbs[(wid * 16 + frow) * 296 + kk * 32 + fk];
    __syncthreads();

    // phase 3: stage g0t (overwrites zbs)
    for (int q = t; q < 18432; q += 256) {          // g0_w[i][o] -> g0t[o][i]
        int i = q >> 6, o = q & 63;
        g0t[o * 296 + i] = f2bf(g0_w[q]);
    }
    __syncthreads();

    // gate layer 0
    #pragma unroll
    for (int nt = 0; nt < 4; ++nt) {
        f32x4 g = {0.f, 0.f, 0.f, 0.f};
        #pragma unroll
        for (int kk = 0; kk < 9; ++kk) {
            bf16x8 b = *(const bf16x8*)&g0t[(nt * 16 + frow) * 296 + kk * 32 + fk];
            g = __builtin_amdgcn_mfma_f32_16x16x32_bf16(A[kk], b, g, 0, 0, 0);
        }
        float bias = g0_b[nt * 16 + frow];
        #pragma unroll
        for (int j = 0; j < 4; ++j)
            hscr[((l >> 4) * 4 + j) * 72 + nt * 16 + frow] = f2bf(elu_f(g[j] + bias));
    }

    // gate layer 1
    {
        bf16x8 hA[2];
        #pragma unroll
        for (int kk = 0; kk < 2; ++kk)
            hA[kk] = *(const bf16x8*)&hscr[frow * 72 + kk * 32 + fk];
        #pragma unroll
        for (int nt = 0; nt < 4; ++nt) {
            f32x4 g = {0.f, 0.f, 0.f, 0.f};
            #pragma unroll
            for (int kk = 0; kk < 2; ++kk) {
                bf16x8 b = *(const bf16x8*)&g1t[(nt * 16 + frow) * 72 + kk * 32 + fk];
                g = __builtin_amdgcn_mfma_f32_16x16x32_bf16(hA[kk], b, g, 0, 0, 0);
            }
            float bias = g1_b[nt * 16 + frow];
            #pragma unroll
            for (int j = 0; j < 4; ++j)
                hscr[((l >> 4) * 4 + j) * 72 + nt * 16 + frow] = f2bf(elu_f(g[j] + bias));
        }
    }

    // gate layer 2 -> logits
    {
        bf16x8 hA[2];
        #pragma unroll
        for (int kk = 0; kk < 2; ++kk)
            hA[kk] = *(const bf16x8*)&hscr[frow * 72 + kk * 32 + fk];
        f32x4 g = {0.f, 0.f, 0.f, 0.f};
        #pragma unroll
        for (int kk = 0; kk < 2; ++kk) {
            bf16x8 b = *(const bf16x8*)&g2t[frow * 72 + kk * 32 + fk];
            g = __builtin_amdgcn_mfma_f32_16x16x32_bf16(hA[kk], b, g, 0, 0, 0);
        }
        if (frow < E_NUM) {
            float bias = g2_b[frow];
            #pragma unroll
            for (int j = 0; j < 4; ++j)
                lgs[(wid * 16 + (l >> 4) * 4 + j) * 8 + frow] = g[j] + bias;
        }
    }
    __syncthreads();

    // softmax + transposed store: coefT[e][b]
    if (t < 64) {
        float m = lgs[t * 8];
        #pragma unroll
        for (int k = 1; k < E_NUM; ++k) m = fmaxf(m, lgs[t * 8 + k]);
        float s = 0.f;
        float ex[E_NUM];
        #pragma unroll
        for (int k = 0; k < E_NUM; ++k) { ex[k] = expf(lgs[t * 8 + k] - m); s += ex[k]; }
        float inv = 1.0f / s;
        #pragma unroll
        for (int k = 0; k < E_NUM; ++k)
            coefT[(size_t)k * B_TOTAL + r0 + t] = ex[k] * inv;
    }
}

// ================= k2: single-wave fragment GEMM =================
// grid (64, 16): wave tile = 32 rows x 16 cols. No LDS, no barriers.
// B-fragments: coalesced 1 KB loads from fragment-major w2tf (L2-resident).
__global__ __launch_bounds__(64) void gemm_frag(
    const float* __restrict__ z, const ushort* __restrict__ w2tf,
    const float* __restrict__ coefT, const float* __restrict__ b2,
    float* __restrict__ out)
{
    const int l  = threadIdx.x;
    const int m0 = blockIdx.x * 32;
    const int nt = blockIdx.y;
    const int n0 = nt * 16;
    const int fr = l & 15, fg = l >> 4;

    // A fragments for rows m0..m0+31 (two 16-row halves), f32 -> bf16
    bf16x8 A0[9], A1[9];
    const float* z0 = z + (size_t)(m0 + fr) * IN_SZ + fg * 8;
    const float* z1 = z0 + 16 * IN_SZ;
    #pragma unroll
    for (int kt = 0; kt < 9; ++kt) {
        float4 v0 = *(const float4*)(z0 + kt * 32);
        float4 v1 = *(const float4*)(z0 + kt * 32 + 4);
        bf16x8 a;
        a[0] = (short)f2bf(v0.x); a[1] = (short)f2bf(v0.y);
        a[2] = (short)f2bf(v0.z); a[3] = (short)f2bf(v0.w);
        a[4] = (short)f2bf(v1.x); a[5] = (short)f2bf(v1.y);
        a[6] = (short)f2bf(v1.z); a[7] = (short)f2bf(v1.w);
        A0[kt] = a;
        float4 w0 = *(const float4*)(z1 + kt * 32);
        float4 w1 = *(const float4*)(z1 + kt * 32 + 4);
        bf16x8 b;
        b[0] = (short)f2bf(w0.x); b[1] = (short)f2bf(w0.y);
        b[2] = (short)f2bf(w0.z); b[3] = (short)f2bf(w0.w);
        b[4] = (short)f2bf(w1.x); b[5] = (short)f2bf(w1.y);
        b[6] = (short)f2bf(w1.z); b[7] = (short)f2bf(w1.w);
        A1[kt] = b;
    }

    f32x4 acc0 = {0.f, 0.f, 0.f, 0.f};
    f32x4 acc1 = {0.f, 0.f, 0.f, 0.f};
    const ushort* fb = w2tf + (size_t)nt * NKT * 512 + l * 8;

    #pragma unroll 2
    for (int e = 0; e < E_NUM; ++e) {
        float4 c0 = *(const float4*)(coefT + (size_t)e * B_TOTAL + m0 + fg * 4);
        float4 c1 = *(const float4*)(coefT + (size_t)e * B_TOTAL + m0 + 16 + fg * 4);
        float bv  = b2[e * OUT_N + n0 + fr];
        f32x4 p0 = {0.f, 0.f, 0.f, 0.f};
        f32x4 p1 = {0.f, 0.f, 0.f, 0.f};
        #pragma unroll
        for (int kt = 0; kt < 9; ++kt) {
            bf16x8 bf = *(const bf16x8*)(fb + ((size_t)e * 16 * NKT + kt) * 512);
            p0 = __builtin_amdgcn_mfma_f32_16x16x32_bf16(A0[kt], bf, p0, 0, 0, 0);
            p1 = __builtin_amdgcn_mfma_f32_16x16x32_bf16(A1[kt], bf, p1, 0, 0, 0);
        }
        float c0a[4] = {c0.x, c0.y, c0.z, c0.w};
        float c1a[4] = {c1.x, c1.y, c1.z, c1.w};
        #pragma unroll
        for (int j = 0; j < 4; ++j) {
            acc0[j] = fmaf(c0a[j], p0[j] + bv, acc0[j]);
            acc1[j] = fmaf(c1a[j], p1[j] + bv, acc1[j]);
        }
    }

    #pragma unroll
    for (int j = 0; j < 4; ++j) {
        out[(size_t)(m0 + fg * 4 + j) * OUT_N + n0 + fr]      = acc0[j];
        out[(size_t)(m0 + 16 + fg * 4 + j) * OUT_N + n0 + fr] = acc1[j];
    }
}

// ================= fallback (ws too small): f32 gate + direct =================
__global__ __launch_bounds__(64) void gate_fb_kernel(
    const float* __restrict__ z,
    const float* __restrict__ g0_w, const float* __restrict__ g0_b,
    const float* __restrict__ g1_w, const float* __restrict__ g1_b,
    const float* __restrict__ g2_w, const float* __restrict__ g2_b,
    float* __restrict__ coef)
{
    __shared__ float z_s[IN_SZ];
    __shared__ float h0_s[GH];
    __shared__ float h1_s[GH];
    const int b = blockIdx.x;
    const int t = threadIdx.x;
    const float* zr = z + (size_t)b * IN_SZ;
    for (int i = t; i < IN_SZ; i += 64) z_s[i] = zr[i];
    __syncthreads();
    float a0 = g0_b[t];
    for (int i = 0; i < IN_SZ; ++i) a0 = fmaf(z_s[i], g0_w[i * GH + t], a0);
    h0_s[t] = elu_f(a0);
    __syncthreads();
    float a1 = g1_b[t];
    for (int k = 0; k < GH; ++k) a1 = fmaf(h0_s[k], g1_w[k * GH + t], a1);
    h1_s[t] = elu_f(a1);
    __syncthreads();
    if (t < E_NUM) {
        float lg = g2_b[t];
        for (int k = 0; k < GH; ++k) lg = fmaf(h1_s[k], g2_w[k * E_NUM + t], lg);
        float m = lg;
        for (int d = 1; d < 8; d <<= 1) m = fmaxf(m, __shfl_xor(m, d, 8));
        float ex = expf(lg - m);
        float s = ex;
        for (int d = 1; d < 8; d <<= 1) s += __shfl_xor(s, d, 8);
        coef[b * E_NUM + t] = ex / s;
    }
}

__global__ __launch_bounds__(256) void direct_kernel(
    const float* __restrict__ z, const float* __restrict__ w2,
    const float* __restrict__ b2, const float* __restrict__ coef,
    float* __restrict__ out)
{
    __shared__ float z_s[8][IN_SZ];
    __shared__ float c_s[8][E_NUM];
    const int b0 = blockIdx.x * 8;
    const int t  = threadIdx.x;
    for (int idx = t; idx < 8 * IN_SZ; idx += 256)
        ((float*)z_s)[idx] = z[(size_t)b0 * IN_SZ + idx];
    if (t < 64) c_s[t >> 3][t & 7] = coef[b0 * E_NUM + t];
    __syncthreads();
    float outv[8];
    #pragma unroll
    for (int r = 0; r < 8; ++r) outv[r] = 0.0f;
    for (int e = 0; e < E_NUM; ++e) {
        const float* w = w2 + (size_t)e * IN_SZ * OUT_N + t;
        float tmp[8];
        #pragma unroll
        for (int r = 0; r < 8; ++r) tmp[r] = 0.0f;
        #pragma unroll 4
        for (int i = 0; i < IN_SZ; ++i) {
            float wv = w[i * OUT_N];
            #pragma unroll
            for (int r = 0; r < 8; ++r) tmp[r] += z_s[r][i] * wv;
        }
        float bv = b2[e * OUT_N + t];
        #pragma unroll
        for (int r = 0; r < 8; ++r) outv[r] += c_s[r][e] * (tmp[r] + bv);
    }
    #pragma unroll
    for (int r = 0; r < 8; ++r) out[(size_t)(b0 + r) * OUT_N + t] = outv[r];
}

extern "C" void kernel_launch(void* const* d_in, const int* in_sizes, int n_in,
                              void* d_out, int out_size, void* d_ws, size_t ws_size,
                              hipStream_t stream) {
    const float* z    = (const float*)d_in[0];
    const float* g0_w = (const float*)d_in[1];
    const float* g0_b = (const float*)d_in[2];
    const float* g1_w = (const float*)d_in[3];
    const float* g1_b = (const float*)d_in[4];
    const float* g2_w = (const float*)d_in[5];
    const float* g2_b = (const float*)d_in[6];
    // d_in[7..10] = w0,b0,w1,b1 are dead in the reference (layer_out never fed back)
    const float* w2   = (const float*)d_in[11];
    const float* b2   = (const float*)d_in[12];
    float* out = (float*)d_out;

    const size_t coefT_b = (size_t)E_NUM * B_TOTAL * sizeof(float);    // 64 KB
    const size_t w2tf_b  = (size_t)E_NUM * 16 * NKT * 1024;            // 1.18 MB

    float*  coefT = (float*)d_ws;
    ushort* w2tf  = (ushort*)((char*)d_ws + coefT_b);

    if (ws_size >= coefT_b + w2tf_b) {
        prep_kernel<<<GATE_BLKS + TR_BLKS, 256, 0, stream>>>(
            z, g0_w, g0_b, g1_w, g1_b, g2_w, g2_b, w2, coefT, w2tf);
        gemm_frag<<<dim3(B_TOTAL / 32, OUT_N / 16), 64, 0, stream>>>(
            z, w2tf, coefT, b2, out);
    } else {
        float* coef = (float*)d_ws;   // needs only 64 KB
        gate_fb_kernel<<<B_TOTAL, 64, 0, stream>>>(z, g0_w, g0_b, g1_w, g1_b,
                                                   g2_w, g2_b, coef);
        direct_kernel<<<B_TOTAL / 8, 256, 0, stream>>>(z, w2, b2, coef, out);
    }
}

// Round 8
// 24.204 us; speedup vs baseline: 1.7896x; 1.7896x over previous
//
#include <hip/hip_runtime.h>
#include <hip/hip_bf16.h>

#define B_TOTAL 2048
#define IN_SZ   288
#define GH      64
#define E_NUM   8
#define OUT_N   256
#define NKT     9                 // k-tiles of 32 per expert

#define W2F_BLKS 72               // one (e,kt) slab each
#define ZF_BLKS  32               // 64 rows each
#define GWF_FRAGS 46              // 36 g0 + 8 g1 + 2 g2

typedef __attribute__((ext_vector_type(8))) short bf16x8;
typedef __attribute__((ext_vector_type(4))) float f32x4;

__device__ __forceinline__ float elu_f(float x) {
    return x > 0.0f ? x : (expf(x) - 1.0f);
}
__device__ __forceinline__ ushort f2bf(float f) {
    __hip_bfloat16 h = __float2bfloat16(f);
    return *reinterpret_cast<ushort*>(&h);
}

// ================= k1: build ALL fragment-major operands =================
// blocks [0,72):      w2 -> w2f frag (e,nt,kt): lane l 16B = cols nt*16+(l&15), k kt*32+(l>>4)*8..+7
// blocks [72,104):    z  -> zf  frag (mt,kt):   lane l 16B = row mt*16+(l&15), same k pattern
// block  104:         gate weights -> gwf frags (same lane pattern; g2 cols 8..15 zero)
__global__ __launch_bounds__(256) void prep_kernel(
    const float* __restrict__ w2, const float* __restrict__ z,
    const float* __restrict__ g0_w, const float* __restrict__ g1_w,
    const float* __restrict__ g2_w,
    ushort* __restrict__ w2f, ushort* __restrict__ zf, ushort* __restrict__ gwf)
{
    __shared__ float ts[32][260];
    const int t = threadIdx.x;
    const int wid = t >> 6, l = t & 63;
    const int fr = l & 15, fg = l >> 4;

    if (blockIdx.x < W2F_BLKS) {
        // ---- w2 fragment transpose (r7-validated) ----
        const int e  = blockIdx.x / NKT;
        const int kt = blockIdx.x - e * NKT;
        const float* src = w2 + ((size_t)e * IN_SZ + kt * 32) * OUT_N;
        #pragma unroll
        for (int q = t; q < 2048; q += 256) {            // 32 rows x 64 float4
            int r = q >> 6, c4 = q & 63;
            *(float4*)&ts[r][c4 * 4] = *(const float4*)(src + (size_t)r * OUT_N + c4 * 4);
        }
        __syncthreads();
        #pragma unroll
        for (int it = 0; it < 4; ++it) {
            int q = t + it * 256;
            int nt = q >> 6, ll = q & 63;
            int qfr = ll & 15, qfg = ll >> 4;
            ushort4 u0, u1;
            u0.x = f2bf(ts[qfg * 8 + 0][nt * 16 + qfr]);
            u0.y = f2bf(ts[qfg * 8 + 1][nt * 16 + qfr]);
            u0.z = f2bf(ts[qfg * 8 + 2][nt * 16 + qfr]);
            u0.w = f2bf(ts[qfg * 8 + 3][nt * 16 + qfr]);
            u1.x = f2bf(ts[qfg * 8 + 4][nt * 16 + qfr]);
            u1.y = f2bf(ts[qfg * 8 + 5][nt * 16 + qfr]);
            u1.z = f2bf(ts[qfg * 8 + 6][nt * 16 + qfr]);
            u1.w = f2bf(ts[qfg * 8 + 7][nt * 16 + qfr]);
            size_t off = ((size_t)((e * 16 + nt) * NKT + kt)) * 512 + ll * 8;
            *(ushort4*)&w2f[off]     = u0;
            *(ushort4*)&w2f[off + 4] = u1;
        }
        return;
    }

    if (blockIdx.x < W2F_BLKS + ZF_BLKS) {
        // ---- z A-fragments: wave handles rowtile mt, 9 frags, batched loads ----
        const int mt = (blockIdx.x - W2F_BLKS) * 4 + wid;   // 0..127
        const int m0 = mt * 16;
        const float* zr = z + (size_t)(m0 + fr) * IN_SZ + fg * 8;
        #pragma unroll
        for (int kt = 0; kt < NKT; ++kt) {
            float4 v0 = *(const float4*)(zr + kt * 32);
            float4 v1 = *(const float4*)(zr + kt * 32 + 4);
            ushort4 u0, u1;
            u0.x = f2bf(v0.x); u0.y = f2bf(v0.y); u0.z = f2bf(v0.z); u0.w = f2bf(v0.w);
            u1.x = f2bf(v1.x); u1.y = f2bf(v1.y); u1.z = f2bf(v1.z); u1.w = f2bf(v1.w);
            size_t off = ((size_t)(mt * NKT + kt)) * 512 + l * 8;
            *(ushort4*)&zf[off]     = u0;
            *(ushort4*)&zf[off + 4] = u1;
        }
        return;
    }

    // ---- gate-weight fragments ----
    for (int fid = wid; fid < GWF_FRAGS; fid += 4) {
        float vals[8];
        if (fid < 36) {
            int nt = fid / NKT, kt = fid - nt * NKT;
            #pragma unroll
            for (int j = 0; j < 8; ++j) {
                int k = kt * 32 + fg * 8 + j;
                vals[j] = g0_w[k * GH + nt * 16 + fr];
            }
        } else if (fid < 44) {
            int q = fid - 36, nt = q >> 1, kk = q & 1;
            #pragma unroll
            for (int j = 0; j < 8; ++j) {
                int k = kk * 32 + fg * 8 + j;
                vals[j] = g1_w[k * GH + nt * 16 + fr];
            }
        } else {
            int kk = fid - 44;
            #pragma unroll
            for (int j = 0; j < 8; ++j) {
                int k = kk * 32 + fg * 8 + j;
                vals[j] = (fr < E_NUM) ? g2_w[k * E_NUM + fr] : 0.0f;
            }
        }
        ushort4 u0, u1;
        u0.x = f2bf(vals[0]); u0.y = f2bf(vals[1]); u0.z = f2bf(vals[2]); u0.w = f2bf(vals[3]);
        u1.x = f2bf(vals[4]); u1.y = f2bf(vals[5]); u1.z = f2bf(vals[6]); u1.w = f2bf(vals[7]);
        size_t off = (size_t)fid * 512 + l * 8;
        *(ushort4*)&gwf[off]     = u0;
        *(ushort4*)&gwf[off + 4] = u1;
    }
}

// ================= k2: gate MLP from fragments -> coefT =================
// 32 blocks x 256 thr; wave = 16 rows. All MFMA operands direct from L2.
__global__ __launch_bounds__(256) void gate_kernel(
    const ushort* __restrict__ zf, const ushort* __restrict__ gwf,
    const float* __restrict__ g0_b, const float* __restrict__ g1_b,
    const float* __restrict__ g2_b,
    float* __restrict__ coefT)
{
    __shared__ ushort hscr_all[4][16][72];
    __shared__ float  lgs[64][8];

    const int t = threadIdx.x, wid = t >> 6, l = t & 63;
    const int fr = l & 15, fg = l >> 4, fk = fg * 8;
    const int r0 = blockIdx.x * 64;
    const int mt = blockIdx.x * 4 + wid;
    ushort (*hscr)[72] = hscr_all[wid];

    bf16x8 A[9];
    #pragma unroll
    for (int kt = 0; kt < NKT; ++kt)
        A[kt] = *(const bf16x8*)(zf + ((size_t)(mt * NKT + kt)) * 512 + l * 8);

    // layer 0: h0[16x64]
    #pragma unroll
    for (int nt = 0; nt < 4; ++nt) {
        f32x4 g = {0.f, 0.f, 0.f, 0.f};
        #pragma unroll
        for (int kt = 0; kt < NKT; ++kt) {
            bf16x8 b = *(const bf16x8*)(gwf + ((size_t)(nt * NKT + kt)) * 512 + l * 8);
            g = __builtin_amdgcn_mfma_f32_16x16x32_bf16(A[kt], b, g, 0, 0, 0);
        }
        float bias = g0_b[nt * 16 + fr];
        #pragma unroll
        for (int j = 0; j < 4; ++j)
            hscr[fg * 4 + j][nt * 16 + fr] = f2bf(elu_f(g[j] + bias));
    }

    // layer 1
    {
        bf16x8 hA[2];
        #pragma unroll
        for (int kk = 0; kk < 2; ++kk)
            hA[kk] = *(const bf16x8*)&hscr[fr][kk * 32 + fk];
        #pragma unroll
        for (int nt = 0; nt < 4; ++nt) {
            f32x4 g = {0.f, 0.f, 0.f, 0.f};
            #pragma unroll
            for (int kk = 0; kk < 2; ++kk) {
                bf16x8 b = *(const bf16x8*)(gwf + ((size_t)(36 + nt * 2 + kk)) * 512 + l * 8);
                g = __builtin_amdgcn_mfma_f32_16x16x32_bf16(hA[kk], b, g, 0, 0, 0);
            }
            float bias = g1_b[nt * 16 + fr];
            #pragma unroll
            for (int j = 0; j < 4; ++j)
                hscr[fg * 4 + j][nt * 16 + fr] = f2bf(elu_f(g[j] + bias));
        }
    }

    // layer 2 -> logits
    {
        bf16x8 hA[2];
        #pragma unroll
        for (int kk = 0; kk < 2; ++kk)
            hA[kk] = *(const bf16x8*)&hscr[fr][kk * 32 + fk];
        f32x4 g = {0.f, 0.f, 0.f, 0.f};
        #pragma unroll
        for (int kk = 0; kk < 2; ++kk) {
            bf16x8 b = *(const bf16x8*)(gwf + ((size_t)(44 + kk)) * 512 + l * 8);
            g = __builtin_amdgcn_mfma_f32_16x16x32_bf16(hA[kk], b, g, 0, 0, 0);
        }
        if (fr < E_NUM) {
            float bias = g2_b[fr];
            #pragma unroll
            for (int j = 0; j < 4; ++j)
                lgs[wid * 16 + fg * 4 + j][fr] = g[j] + bias;
        }
    }
    __syncthreads();

    // softmax per row -> coefT[e][b]
    if (t < 64) {
        float m = lgs[t][0];
        #pragma unroll
        for (int k = 1; k < E_NUM; ++k) m = fmaxf(m, lgs[t][k]);
        float s = 0.f;
        float ex[E_NUM];
        #pragma unroll
        for (int k = 0; k < E_NUM; ++k) { ex[k] = expf(lgs[t][k] - m); s += ex[k]; }
        float inv = 1.0f / s;
        #pragma unroll
        for (int k = 0; k < E_NUM; ++k)
            coefT[(size_t)k * B_TOTAL + r0 + t] = ex[k] * inv;
    }
}

// ================= k3: single-wave 16x16 GEMM, all experts, frag loads =================
// grid (128, 16), 64 thr. 2048 blocks = 8 blocks/CU. B double-buffered over experts.
__global__ __launch_bounds__(64) void gemm_kernel(
    const ushort* __restrict__ zf, const ushort* __restrict__ w2f,
    const float* __restrict__ coefT, const float* __restrict__ b2,
    float* __restrict__ out)
{
    const int l = threadIdx.x, fr = l & 15, fg = l >> 4;
    const int mt = blockIdx.x, m0 = mt * 16;
    const int nt = blockIdx.y, n0 = nt * 16;

    bf16x8 A[9];
    #pragma unroll
    for (int kt = 0; kt < NKT; ++kt)
        A[kt] = *(const bf16x8*)(zf + ((size_t)(mt * NKT + kt)) * 512 + l * 8);

    const ushort* Bp = w2f + (size_t)nt * NKT * 512 + l * 8;

    f32x4 acc = {0.f, 0.f, 0.f, 0.f};
    bf16x8 B[9];
    #pragma unroll
    for (int kt = 0; kt < NKT; ++kt)
        B[kt] = *(const bf16x8*)(Bp + (size_t)kt * 512);

    #pragma unroll
    for (int e = 0; e < E_NUM; ++e) {
        bf16x8 Bn[9];
        if (e < E_NUM - 1) {
            #pragma unroll
            for (int kt = 0; kt < NKT; ++kt)
                Bn[kt] = *(const bf16x8*)(Bp + ((size_t)(e + 1) * 16 * NKT + kt) * 512);
        }
        // two interleaved accumulator chains for ILP
        f32x4 p0 = {0.f, 0.f, 0.f, 0.f};
        f32x4 p1 = {0.f, 0.f, 0.f, 0.f};
        p0 = __builtin_amdgcn_mfma_f32_16x16x32_bf16(A[0], B[0], p0, 0, 0, 0);
        p1 = __builtin_amdgcn_mfma_f32_16x16x32_bf16(A[1], B[1], p1, 0, 0, 0);
        p0 = __builtin_amdgcn_mfma_f32_16x16x32_bf16(A[2], B[2], p0, 0, 0, 0);
        p1 = __builtin_amdgcn_mfma_f32_16x16x32_bf16(A[3], B[3], p1, 0, 0, 0);
        p0 = __builtin_amdgcn_mfma_f32_16x16x32_bf16(A[4], B[4], p0, 0, 0, 0);
        p1 = __builtin_amdgcn_mfma_f32_16x16x32_bf16(A[5], B[5], p1, 0, 0, 0);
        p0 = __builtin_amdgcn_mfma_f32_16x16x32_bf16(A[6], B[6], p0, 0, 0, 0);
        p1 = __builtin_amdgcn_mfma_f32_16x16x32_bf16(A[7], B[7], p1, 0, 0, 0);
        p0 = __builtin_amdgcn_mfma_f32_16x16x32_bf16(A[8], B[8], p0, 0, 0, 0);

        float4 cv = *(const float4*)(coefT + (size_t)e * B_TOTAL + m0 + fg * 4);
        float bv  = b2[e * OUT_N + n0 + fr];
        float ca[4] = {cv.x, cv.y, cv.z, cv.w};
        #pragma unroll
        for (int j = 0; j < 4; ++j)
            acc[j] = fmaf(ca[j], p0[j] + p1[j] + bv, acc[j]);

        #pragma unroll
        for (int kt = 0; kt < NKT; ++kt) B[kt] = Bn[kt];
    }

    #pragma unroll
    for (int j = 0; j < 4; ++j)
        out[(size_t)(m0 + fg * 4 + j) * OUT_N + n0 + fr] = acc[j];
}

// ================= fallback (ws too small): f32 gate + direct =================
__global__ __launch_bounds__(64) void gate_fb_kernel(
    const float* __restrict__ z,
    const float* __restrict__ g0_w, const float* __restrict__ g0_b,
    const float* __restrict__ g1_w, const float* __restrict__ g1_b,
    const float* __restrict__ g2_w, const float* __restrict__ g2_b,
    float* __restrict__ coef)
{
    __shared__ float z_s[IN_SZ];
    __shared__ float h0_s[GH];
    __shared__ float h1_s[GH];
    const int b = blockIdx.x;
    const int t = threadIdx.x;
    const float* zr = z + (size_t)b * IN_SZ;
    for (int i = t; i < IN_SZ; i += 64) z_s[i] = zr[i];
    __syncthreads();
    float a0 = g0_b[t];
    for (int i = 0; i < IN_SZ; ++i) a0 = fmaf(z_s[i], g0_w[i * GH + t], a0);
    h0_s[t] = elu_f(a0);
    __syncthreads();
    float a1 = g1_b[t];
    for (int k = 0; k < GH; ++k) a1 = fmaf(h0_s[k], g1_w[k * GH + t], a1);
    h1_s[t] = elu_f(a1);
    __syncthreads();
    if (t < E_NUM) {
        float lg = g2_b[t];
        for (int k = 0; k < GH; ++k) lg = fmaf(h1_s[k], g2_w[k * E_NUM + t], lg);
        float m = lg;
        for (int d = 1; d < 8; d <<= 1) m = fmaxf(m, __shfl_xor(m, d, 8));
        float ex = expf(lg - m);
        float s = ex;
        for (int d = 1; d < 8; d <<= 1) s += __shfl_xor(s, d, 8);
        coef[b * E_NUM + t] = ex / s;
    }
}

__global__ __launch_bounds__(256) void direct_kernel(
    const float* __restrict__ z, const float* __restrict__ w2,
    const float* __restrict__ b2, const float* __restrict__ coef,
    float* __restrict__ out)
{
    __shared__ float z_s[8][IN_SZ];
    __shared__ float c_s[8][E_NUM];
    const int b0 = blockIdx.x * 8;
    const int t  = threadIdx.x;
    for (int idx = t; idx < 8 * IN_SZ; idx += 256)
        ((float*)z_s)[idx] = z[(size_t)b0 * IN_SZ + idx];
    if (t < 64) c_s[t >> 3][t & 7] = coef[b0 * E_NUM + t];
    __syncthreads();
    float outv[8];
    #pragma unroll
    for (int r = 0; r < 8; ++r) outv[r] = 0.0f;
    for (int e = 0; e < E_NUM; ++e) {
        const float* w = w2 + (size_t)e * IN_SZ * OUT_N + t;
        float tmp[8];
        #pragma unroll
        for (int r = 0; r < 8; ++r) tmp[r] = 0.0f;
        #pragma unroll 4
        for (int i = 0; i < IN_SZ; ++i) {
            float wv = w[i * OUT_N];
            #pragma unroll
            for (int r = 0; r < 8; ++r) tmp[r] += z_s[r][i] * wv;
        }
        float bv = b2[e * OUT_N + t];
        #pragma unroll
        for (int r = 0; r < 8; ++r) outv[r] += c_s[r][e] * (tmp[r] + bv);
    }
    #pragma unroll
    for (int r = 0; r < 8; ++r) out[(size_t)(b0 + r) * OUT_N + t] = outv[r];
}

extern "C" void kernel_launch(void* const* d_in, const int* in_sizes, int n_in,
                              void* d_out, int out_size, void* d_ws, size_t ws_size,
                              hipStream_t stream) {
    const float* z    = (const float*)d_in[0];
    const float* g0_w = (const float*)d_in[1];
    const float* g0_b = (const float*)d_in[2];
    const float* g1_w = (const float*)d_in[3];
    const float* g1_b = (const float*)d_in[4];
    const float* g2_w = (const float*)d_in[5];
    const float* g2_b = (const float*)d_in[6];
    // d_in[7..10] = w0,b0,w1,b1 are dead in the reference (layer_out never fed back)
    const float* w2   = (const float*)d_in[11];
    const float* b2   = (const float*)d_in[12];
    float* out = (float*)d_out;

    const size_t w2f_b   = (size_t)E_NUM * 16 * NKT * 1024;          // 1.18 MB
    const size_t zf_b    = (size_t)128 * NKT * 1024;                 // 1.18 MB
    const size_t gwf_b   = (size_t)GWF_FRAGS * 1024;                 // 47 KB
    const size_t coefT_b = (size_t)E_NUM * B_TOTAL * sizeof(float);  // 64 KB

    char* p = (char*)d_ws;
    ushort* w2f   = (ushort*)p;            p += w2f_b;
    ushort* zf    = (ushort*)p;            p += zf_b;
    ushort* gwf   = (ushort*)p;            p += gwf_b;
    float*  coefT = (float*)p;

    if (ws_size >= w2f_b + zf_b + gwf_b + coefT_b) {
        prep_kernel<<<W2F_BLKS + ZF_BLKS + 1, 256, 0, stream>>>(
            w2, z, g0_w, g1_w, g2_w, w2f, zf, gwf);
        gate_kernel<<<32, 256, 0, stream>>>(zf, gwf, g0_b, g1_b, g2_b, coefT);
        gemm_kernel<<<dim3(B_TOTAL / 16, OUT_N / 16), 64, 0, stream>>>(
            zf, w2f, coefT, b2, out);
    } else {
        float* coef = (float*)d_ws;
        gate_fb_kernel<<<B_TOTAL, 64, 0, stream>>>(z, g0_w, g0_b, g1_w, g1_b,
                                                   g2_w, g2_b, coef);
        direct_kernel<<<B_TOTAL / 8, 256, 0, stream>>>(z, w2, b2, coef, out);
    }
}